// Round 1
// baseline (632.833 us; speedup 1.0000x reference)
//
#include <hip/hip_runtime.h>
#include <stdint.h>

// Problem constants
// B=8, H=128, W=128, C=256, HEADS=8, WIN=8, HALO=8, BLOCK=4, PAD=2
// QK_U=32, QK_CH=256, KV_CH=512, M = 8*128*128 = 131072

typedef __attribute__((ext_vector_type(8))) short short8;
typedef __attribute__((ext_vector_type(4))) short short4v;
typedef __attribute__((ext_vector_type(4))) float f32x4;

__device__ __forceinline__ float bf2f(unsigned short u){
  union { unsigned int i; float f; } x; x.i = ((unsigned int)u)<<16; return x.f;
}
__device__ __forceinline__ unsigned short f2bf(float f){
  union { float f; unsigned int i; } x; x.f = f;
  unsigned int r = x.i + 0x7FFFu + ((x.i>>16)&1u);
  return (unsigned short)(r>>16);
}

// ---------------- weight transpose + bf16 convert: wt[n][k] = w[k][n] --------
__global__ void transpose_w_kernel(const float* __restrict__ w, short* __restrict__ wt,
                                   int K, int N)
{
  int idx = blockIdx.x*256 + threadIdx.x;
  if (idx >= K*N) return;
  int n = idx / K, k = idx - n*K;
  wt[idx] = (short)f2bf(w[(long)k*N + n]);
}

// ---------------- relative position bias table: out[8][64][64] --------------
__global__ __launch_bounds__(64) void relbias_kernel(const float* __restrict__ w1,
    const float* __restrict__ b1, const float* __restrict__ w2, float* __restrict__ out)
{
  int q = blockIdx.x;   // 0..63  (qy*8+qx)
  int k = threadIdx.x;  // 0..63  (ky*8+kx)
  float ry = (float)(q>>3) - (((float)(k>>3) - 2.f)*2.f + 0.5f);
  float rx = (float)(q&7)  - (((float)(k&7)  - 2.f)*2.f + 0.5f);
  ry *= (8.f/7.f); rx *= (8.f/7.f);
  float sy = (ry>0.f)?1.f:((ry<0.f)?-1.f:0.f);
  float sx = (rx>0.f)?1.f:((rx<0.f)?-1.f:0.f);
  ry = sy * log2f(fabsf(ry)+1.f) * (1.f/3.f);
  rx = sx * log2f(fabsf(rx)+1.f) * (1.f/3.f);
  float acc[8] = {0,0,0,0,0,0,0,0};
  for (int j=0;j<512;j++){
    float hm = ry*w1[j] + rx*w1[512+j] + b1[j];
    hm = fmaxf(hm, 0.f);
#pragma unroll
    for (int h=0;h<8;h++) acc[h] += hm * w2[j*8+h];
  }
#pragma unroll
  for (int h=0;h<8;h++)
    out[h*4096 + q*64 + k] = 16.f / (1.f + __expf(-acc[h]));
}

// ---------------- GEMM: C[M x ND] = A[M x KD] * Bt[ND x KD]^T ----------------
// MODE 0: A is f32 (inputs). Output split: col<256 -> out_q (+bias), else out_kv (bf16)
// MODE 1: A is bf16.       Output f32: out_f = val + bias[col]
template<int KD, int ND, int MODE>
__global__ __launch_bounds__(256) void gemm_bt_kernel(const void* __restrict__ Av,
    const short* __restrict__ Bt, const float* __restrict__ bias,
    short* __restrict__ out_q, short* __restrict__ out_kv, float* __restrict__ out_f)
{
  __shared__ short As[128*64];
  __shared__ short Bs[128*64];
  const int tid  = threadIdx.x;
  const int lane = tid & 63;
  const int wid  = tid >> 6;
  const int wr = wid >> 1, wc = wid & 1;
  const long row0 = (long)blockIdx.y * 128;
  const int  col0 = blockIdx.x * 128;

  f32x4 acc[4][4];
#pragma unroll
  for (int m=0;m<4;m++)
#pragma unroll
    for (int n=0;n<4;n++) acc[m][n] = (f32x4){0.f,0.f,0.f,0.f};

  for (int kt = 0; kt < KD; kt += 64) {
    __syncthreads();
    if (MODE == 0) {
      const float* A = (const float*)Av;
#pragma unroll
      for (int i = 0; i < 8; i++) {
        int flat = i*256 + tid;
        int r = flat >> 4, c4 = flat & 15;
        const float4 v = *(const float4*)(A + (row0 + r)*KD + kt + c4*4);
        short4v pk;
        pk[0] = (short)f2bf(v.x); pk[1] = (short)f2bf(v.y);
        pk[2] = (short)f2bf(v.z); pk[3] = (short)f2bf(v.w);
        int addr = r*64 + (((c4>>1) ^ (r&7))<<3) + ((c4&1)<<2);
        *(short4v*)(As + addr) = pk;
      }
    } else {
      const short* A = (const short*)Av;
#pragma unroll
      for (int i = 0; i < 4; i++) {
        int flat = i*256 + tid;
        int r = flat >> 3, c8 = flat & 7;
        short8 v = *(const short8*)(A + (row0 + r)*KD + kt + c8*8);
        *(short8*)(As + r*64 + ((c8 ^ (r&7))<<3)) = v;
      }
    }
#pragma unroll
    for (int i = 0; i < 4; i++) {
      int flat = i*256 + tid;
      int r = flat >> 3, c8 = flat & 7;
      short8 v = *(const short8*)(Bt + (long)(col0 + r)*KD + kt + c8*8);
      *(short8*)(Bs + r*64 + ((c8 ^ (r&7))<<3)) = v;
    }
    __syncthreads();
#pragma unroll
    for (int ks = 0; ks < 2; ks++) {
      short8 af[4], bfv[4];
#pragma unroll
      for (int m=0;m<4;m++){
        int r = wr*64 + m*16 + (lane & 15);
        int g = ks*4 + (lane >> 4);
        af[m] = *(const short8*)(As + r*64 + ((g ^ (r&7))<<3));
      }
#pragma unroll
      for (int n=0;n<4;n++){
        int r = wc*64 + n*16 + (lane & 15);
        int g = ks*4 + (lane >> 4);
        bfv[n] = *(const short8*)(Bs + r*64 + ((g ^ (r&7))<<3));
      }
#pragma unroll
      for (int m=0;m<4;m++)
#pragma unroll
        for (int n=0;n<4;n++)
          acc[m][n] = __builtin_amdgcn_mfma_f32_16x16x32_bf16(af[m], bfv[n], acc[m][n], 0, 0, 0);
    }
  }
  // epilogue: C/D layout col=lane&15, row=(lane>>4)*4+reg
#pragma unroll
  for (int m=0;m<4;m++){
    long rowb = row0 + wr*64 + m*16 + ((lane>>4)<<2);
#pragma unroll
    for (int n=0;n<4;n++){
      int col = col0 + wc*64 + n*16 + (lane&15);
#pragma unroll
      for (int rg=0;rg<4;rg++){
        float v = acc[m][n][rg];
        long r = rowb + rg;
        if (MODE == 0) {
          if (col < 256) out_q[r*256 + col] = (short)f2bf(v + bias[col]);
          else           out_kv[r*512 + (col-256)] = (short)f2bf(v);
        } else {
          out_f[r*ND + col] = v + bias[col];
        }
      }
    }
  }
}

// ---------------- depthwise 3x3 stride-2 conv + BN + v_bias ------------------
// in: kv_buf bf16 (8,128,128,512) -> out: kv_ds bf16 (8,64,64,512)
__global__ __launch_bounds__(256) void dwconv_kernel(const short* __restrict__ kv_buf,
    const float* __restrict__ dw_w, const float* __restrict__ gamma,
    const float* __restrict__ beta, const float* __restrict__ mean,
    const float* __restrict__ var, const float* __restrict__ v_bias,
    short* __restrict__ kv_ds)
{
  int bid = blockIdx.x;             // 8*64*8 = 4096
  int b = bid >> 9, rem = bid & 511;
  int y2 = rem >> 3, xb = rem & 7;
  int tid = threadIdx.x;
  int cg = tid & 31, xl = tid >> 5;
  int x2 = xb*8 + xl;
  int ch0 = cg*16;
  float acc[16];
#pragma unroll
  for (int i=0;i<16;i++) acc[i] = 0.f;
#pragma unroll
  for (int dy=0; dy<3; dy++){
    int y = y2*2 + dy;
    if (y >= 128) continue;
#pragma unroll
    for (int dx=0; dx<3; dx++){
      int x = x2*2 + dx;
      if (x >= 128) continue;
      const short* p = kv_buf + ((long)((b*128+y)*128 + x))*512 + ch0;
      short8 v0 = *(const short8*)p;
      short8 v1 = *(const short8*)(p+8);
      const float* wp = dw_w + (dy*3+dx)*512 + ch0;
#pragma unroll
      for (int i=0;i<8;i++) acc[i]   += bf2f((unsigned short)v0[i]) * wp[i];
#pragma unroll
      for (int i=0;i<8;i++) acc[8+i] += bf2f((unsigned short)v1[i]) * wp[8+i];
    }
  }
  short8 r0, r1;
#pragma unroll
  for (int i=0;i<16;i++){
    int c = ch0 + i;
    float r = (acc[i]-mean[c]) * rsqrtf(var[c]+1e-3f) * gamma[c] + beta[c];
    if (c >= 256) r += v_bias[c-256];
    if (i<8) r0[i] = (short)f2bf(r); else r1[i-8] = (short)f2bf(r);
  }
  short* o = kv_ds + ((long)((b*64+y2)*64 + x2))*512 + ch0;
  *(short8*)o = r0;
  *(short8*)(o+8) = r1;
}

// ---------------- halo attention --------------------------------------------
// grid: 2048 (= 8 batch * 256 windows); block: 256 (4 waves, each 2 heads)
__global__ __launch_bounds__(256) void halo_attn_kernel(const short* __restrict__ q_buf,
    const short* __restrict__ kv_ds, const float* __restrict__ relb,
    const float* __restrict__ scale, short* __restrict__ attn_out)
{
  __shared__ float qss[8][64];
  __shared__ float kss[8][64];
  __shared__ short vts[4][32][72];  // per-wave V^T [dim][key], 144B rows (16B aligned)
  __shared__ short ps [4][64][72];  // per-wave P   [query][key]

  const int bid = blockIdx.x;
  const int b = bid >> 8, wno = bid & 255;
  const int bi = wno >> 4, bj = wno & 15;
  const int tid = threadIdx.x;
  const int w = tid >> 6, lane = tid & 63;

  // ---- sum-of-squares prepass (for post-hoc l2 normalization) ----
#pragma unroll
  for (int i=0;i<4;i++){
    int idx = i*256 + tid;        // 0..1023: [0,512) q rows, [512,1024) k rows
    int isk = idx >> 9;
    int h   = (idx >> 6) & 7;
    int row = idx & 63;
    float ss = 0.f;
    if (!isk) {
      int qy = row>>3, qx = row&7;
      const short* p = q_buf + ((long)((b*128 + bi*8 + qy)*128 + (bj*8+qx)))*256 + h*32;
#pragma unroll
      for (int j=0;j<4;j++){
        short8 v = *(const short8*)(p + j*8);
#pragma unroll
        for (int e=0;e<8;e++){ float f = bf2f((unsigned short)v[e]); ss += f*f; }
      }
      qss[h][row] = fmaxf(ss, 1.55e-5f);
    } else {
      int ky = row>>3, kx = row&7;
      int yy = bi*4 - 2 + ky, xx = bj*4 - 2 + kx;
      if (yy>=0 && yy<64 && xx>=0 && xx<64) {
        const short* p = kv_ds + ((long)((b*64+yy)*64+xx))*512 + h*32;
#pragma unroll
        for (int j=0;j<4;j++){
          short8 v = *(const short8*)(p + j*8);
#pragma unroll
          for (int e=0;e<8;e++){ float f = bf2f((unsigned short)v[e]); ss += f*f; }
        }
      }
      kss[h][row] = fmaxf(ss, 1.55e-5f);
    }
  }
  __syncthreads();

  const short8 zero8 = {0,0,0,0,0,0,0,0};

  for (int hi=0; hi<2; hi++){
    int h = w + hi*4;
    float lscale = __expf(fminf(scale[h], 4.6051702f)); // exp(min(s, ln 100))

    // ---- stage V^T (per wave) ----
#pragma unroll 4
    for (int j=0;j<32;j++){
      int flat = j*64 + lane;
      int key = flat >> 5, d = flat & 31;
      int ky = key>>3, kx = key&7;
      int yy = bi*4-2+ky, xx = bj*4-2+kx;
      short val = 0;
      if (yy>=0 && yy<64 && xx>=0 && xx<64)
        val = kv_ds[((long)((b*64+yy)*64+xx))*512 + 256 + h*32 + d];
      vts[w][d][key] = val;
    }

    // ---- S^T = K * Q^T  (raw, unnormalized) ----
    short8 af[4], bfv[4];
#pragma unroll
    for (int m=0;m<4;m++){
      int key = m*16 + (lane&15);
      int ky = key>>3, kx = key&7;
      int yy = bi*4-2+ky, xx = bj*4-2+kx;
      if (yy>=0 && yy<64 && xx>=0 && xx<64)
        af[m] = *(const short8*)(kv_ds + ((long)((b*64+yy)*64+xx))*512 + h*32 + ((lane>>4)<<3));
      else
        af[m] = zero8;
    }
#pragma unroll
    for (int n=0;n<4;n++){
      int q = n*16 + (lane&15);
      int qy = q>>3, qx = q&7;
      bfv[n] = *(const short8*)(q_buf + ((long)((b*128+bi*8+qy)*128 + bj*8+qx))*256 + h*32 + ((lane>>4)<<3));
    }
    f32x4 sc_[4][4];
#pragma unroll
    for (int m=0;m<4;m++)
#pragma unroll
      for (int n=0;n<4;n++)
        sc_[m][n] = __builtin_amdgcn_mfma_f32_16x16x32_bf16(af[m], bfv[n],
                        (f32x4){0.f,0.f,0.f,0.f}, 0, 0, 0);

    // ---- logits: scale + rel bias + pad mask; key=m*16+(lane>>4)*4+reg, query=n*16+(lane&15)
    float rq[4];
#pragma unroll
    for (int n=0;n<4;n++) rq[n] = rsqrtf(qss[h][n*16 + (lane&15)]);
    float mx[4] = {-1e30f,-1e30f,-1e30f,-1e30f};
#pragma unroll
    for (int m=0;m<4;m++){
      int key0 = m*16 + ((lane>>4)<<2);
      float rk[4], mk[4];
#pragma unroll
      for (int r=0;r<4;r++){
        int key = key0 + r;
        int ky = key>>3, kx = key&7;
        int yy = bi*4-2+ky, xx = bj*4-2+kx;
        rk[r] = rsqrtf(kss[h][key]);
        mk[r] = (yy>=0 && yy<64 && xx>=0 && xx<64) ? 0.f : -100.f;
      }
#pragma unroll
      for (int n=0;n<4;n++){
        int q = n*16 + (lane&15);
        f32x4 rb = *(const f32x4*)(relb + h*4096 + q*64 + key0);
#pragma unroll
        for (int r=0;r<4;r++){
          float v = sc_[m][n][r] * (rk[r]*rq[n]*lscale) + rb[r] + mk[r];
          sc_[m][n][r] = v;
          mx[n] = fmaxf(mx[n], v);
        }
      }
    }
#pragma unroll
    for (int n=0;n<4;n++){
      mx[n] = fmaxf(mx[n], __shfl_xor(mx[n], 16));
      mx[n] = fmaxf(mx[n], __shfl_xor(mx[n], 32));
    }
    float sm[4] = {0.f,0.f,0.f,0.f};
#pragma unroll
    for (int m=0;m<4;m++)
#pragma unroll
      for (int n=0;n<4;n++)
#pragma unroll
        for (int r=0;r<4;r++){
          float e = __expf(sc_[m][n][r] - mx[n]);
          sc_[m][n][r] = e;
          sm[n] += e;
        }
#pragma unroll
    for (int n=0;n<4;n++){
      sm[n] += __shfl_xor(sm[n], 16);
      sm[n] += __shfl_xor(sm[n], 32);
      sm[n] = 1.f / sm[n];
    }
    // ---- write P[query][key] (consecutive regs are consecutive keys -> b64) ----
#pragma unroll
    for (int n=0;n<4;n++){
      int q = n*16 + (lane&15);
#pragma unroll
      for (int m=0;m<4;m++){
        short4v pk;
#pragma unroll
        for (int r=0;r<4;r++) pk[r] = (short)f2bf(sc_[m][n][r] * sm[n]);
        *(short4v*)(&ps[w][q][m*16 + ((lane>>4)<<2)]) = pk;
      }
    }
    __syncthreads();

    // ---- O = P * V ----
    f32x4 oc[4][2];
#pragma unroll
    for (int m=0;m<4;m++)
#pragma unroll
      for (int n=0;n<2;n++) oc[m][n] = (f32x4){0.f,0.f,0.f,0.f};
#pragma unroll
    for (int ks=0; ks<2; ks++){
      short8 pa[4], vb[2];
#pragma unroll
      for (int m=0;m<4;m++)
        pa[m] = *(const short8*)(&ps[w][m*16 + (lane&15)][ks*32 + ((lane>>4)<<3)]);
#pragma unroll
      for (int n=0;n<2;n++)
        vb[n] = *(const short8*)(&vts[w][n*16 + (lane&15)][ks*32 + ((lane>>4)<<3)]);
#pragma unroll
      for (int m=0;m<4;m++)
#pragma unroll
        for (int n=0;n<2;n++)
          oc[m][n] = __builtin_amdgcn_mfma_f32_16x16x32_bf16(pa[m], vb[n], oc[m][n], 0, 0, 0);
    }
    // ---- store: query=m*16+(lane>>4)*4+reg, dim=n*16+(lane&15) ----
#pragma unroll
    for (int m=0;m<4;m++){
      int q0 = m*16 + ((lane>>4)<<2);
#pragma unroll
      for (int n=0;n<2;n++){
        int d = n*16 + (lane&15);
#pragma unroll
        for (int r=0;r<4;r++){
          int q = q0 + r;
          int qy = q>>3, qx = q&7;
          attn_out[((long)((b*128 + bi*8+qy)*128 + bj*8+qx))*256 + h*32 + d] =
              (short)f2bf(oc[m][n][r]);
        }
      }
    }
    __syncthreads();
  }
}

// ---------------- launch -----------------------------------------------------
extern "C" void kernel_launch(void* const* d_in, const int* in_sizes, int n_in,
                              void* d_out, int out_size, void* d_ws, size_t ws_size,
                              hipStream_t stream)
{
  (void)in_sizes; (void)n_in; (void)out_size; (void)ws_size;
  const float* inputs = (const float*)d_in[0];
  const float* qkv_w  = (const float*)d_in[1];
  const float* q_bias = (const float*)d_in[2];
  const float* v_bias = (const float*)d_in[3];
  const float* dw_w   = (const float*)d_in[4];
  const float* dw_g   = (const float*)d_in[5];
  const float* dw_b   = (const float*)d_in[6];
  const float* dw_m   = (const float*)d_in[7];
  const float* dw_v   = (const float*)d_in[8];
  const float* scale  = (const float*)d_in[9];
  const float* cpb_w1 = (const float*)d_in[10];
  const float* cpb_b1 = (const float*)d_in[11];
  const float* cpb_w2 = (const float*)d_in[12];
  const float* proj_w = (const float*)d_in[13];
  const float* proj_b = (const float*)d_in[14];

  char* ws = (char*)d_ws;
  short* q_buf    = (short*)(ws);                  //  64 MiB  (131072 x 256 bf16)
  short* kv_buf   = (short*)(ws + 67108864L);      // 128 MiB  (131072 x 512 bf16)
  short* kv_ds    = (short*)(ws + 201326592L);     //  32 MiB  (8x64x64x512 bf16)
  short* attn_buf = (short*)(ws + 234881024L);     //  64 MiB  (131072 x 256 bf16)
  short* qkvw_t   = (short*)(ws + 301989888L);     // 384 KiB  (768 x 256 bf16)
  short* projw_t  = (short*)(ws + 302383104L);     // 128 KiB  (256 x 256 bf16)
  float* relb     = (float*)(ws + 302514176L);     // 128 KiB  (8 x 64 x 64 f32)

  transpose_w_kernel<<<768, 256, 0, stream>>>(qkv_w, qkvw_t, 256, 768);
  transpose_w_kernel<<<256, 256, 0, stream>>>(proj_w, projw_t, 256, 256);
  relbias_kernel<<<64, 64, 0, stream>>>(cpb_w1, cpb_b1, cpb_w2, relb);

  gemm_bt_kernel<256, 768, 0><<<dim3(6, 1024), 256, 0, stream>>>(
      inputs, qkvw_t, q_bias, q_buf, kv_buf, nullptr);

  dwconv_kernel<<<4096, 256, 0, stream>>>(kv_buf, dw_w, dw_g, dw_b, dw_m, dw_v, v_bias, kv_ds);

  halo_attn_kernel<<<2048, 256, 0, stream>>>(q_buf, kv_ds, relb, scale, attn_buf);

  gemm_bt_kernel<256, 256, 1><<<dim3(2, 1024), 256, 0, stream>>>(
      attn_buf, projw_t, proj_b, nullptr, nullptr, (float*)d_out);
}

// Round 2
// 592.243 us; speedup vs baseline: 1.0685x; 1.0685x over previous
//
#include <hip/hip_runtime.h>
#include <stdint.h>

// Problem constants
// B=8, H=128, W=128, C=256, HEADS=8, WIN=8, HALO=8, BLOCK=4, PAD=2
// QK_U=32, QK_CH=256, KV_CH=512, M = 8*128*128 = 131072

typedef __attribute__((ext_vector_type(8))) short short8;
typedef __attribute__((ext_vector_type(4))) short short4v;
typedef __attribute__((ext_vector_type(4))) float f32x4;

__device__ __forceinline__ float bf2f(unsigned short u){
  union { unsigned int i; float f; } x; x.i = ((unsigned int)u)<<16; return x.f;
}
__device__ __forceinline__ unsigned short f2bf(float f){
  union { float f; unsigned int i; } x; x.f = f;
  unsigned int r = x.i + 0x7FFFu + ((x.i>>16)&1u);
  return (unsigned short)(r>>16);
}
__device__ __forceinline__ void gl_lds16(const void* g, void* l){
  __builtin_amdgcn_global_load_lds((const __attribute__((address_space(1))) unsigned int*)g,
                                   (__attribute__((address_space(3))) unsigned int*)l, 16, 0, 0);
}

// ---------------- weight transpose + bf16 convert: wt[n][k] = w[k][n] --------
__global__ void transpose_w_kernel(const float* __restrict__ w, short* __restrict__ wt,
                                   int K, int N)
{
  int idx = blockIdx.x*256 + threadIdx.x;
  if (idx >= K*N) return;
  int n = idx / K, k = idx - n*K;
  wt[idx] = (short)f2bf(w[(long)k*N + n]);
}

// ---------------- relative position bias table: out[8][64][64] --------------
__global__ __launch_bounds__(64) void relbias_kernel(const float* __restrict__ w1,
    const float* __restrict__ b1, const float* __restrict__ w2, float* __restrict__ out)
{
  int q = blockIdx.x;   // 0..63  (qy*8+qx)
  int k = threadIdx.x;  // 0..63  (ky*8+kx)
  float ry = (float)(q>>3) - (((float)(k>>3) - 2.f)*2.f + 0.5f);
  float rx = (float)(q&7)  - (((float)(k&7)  - 2.f)*2.f + 0.5f);
  ry *= (8.f/7.f); rx *= (8.f/7.f);
  float sy = (ry>0.f)?1.f:((ry<0.f)?-1.f:0.f);
  float sx = (rx>0.f)?1.f:((rx<0.f)?-1.f:0.f);
  ry = sy * log2f(fabsf(ry)+1.f) * (1.f/3.f);
  rx = sx * log2f(fabsf(rx)+1.f) * (1.f/3.f);
  float acc[8] = {0,0,0,0,0,0,0,0};
  for (int j=0;j<512;j++){
    float hm = ry*w1[j] + rx*w1[512+j] + b1[j];
    hm = fmaxf(hm, 0.f);
#pragma unroll
    for (int h=0;h<8;h++) acc[h] += hm * w2[j*8+h];
  }
#pragma unroll
  for (int h=0;h<8;h++)
    out[h*4096 + q*64 + k] = 16.f / (1.f + __expf(-acc[h]));
}

// ---------------- GEMM: C[M x ND] = A[M x KD] * Bt[ND x KD]^T ----------------
// MODE 0: A is f32 (inputs). Output split: col<256 -> out_q (+bias), else out_kv (bf16)
// MODE 1: A is bf16.       Output f32: out_f = val + bias[col]
// 1-D grid with bijective XCD swizzle: the ND/128 column blocks of each row
// block run consecutively on the SAME XCD -> A panel stays L2-hot.
template<int KD, int ND, int MODE>
__global__ __launch_bounds__(256) void gemm_bt_kernel(const void* __restrict__ Av,
    const short* __restrict__ Bt, const float* __restrict__ bias,
    short* __restrict__ out_q, short* __restrict__ out_kv, float* __restrict__ out_f)
{
  __shared__ short smem[128*128];          // As = smem[0:8192), Bs = smem[8192:16384)
  short* As = smem;
  short* Bs = smem + 128*64;

  const int tid  = threadIdx.x;
  const int lane = tid & 63;
  const int wid  = tid >> 6;
  const int wr = wid >> 1, wc = wid & 1;

  constexpr int NCB = ND / 128;            // column blocks per row block
  const int bid = blockIdx.x;
  const int xcd = bid & 7;
  const int idx = bid >> 3;                // 0 .. 128*NCB-1 per xcd
  const long row0 = (long)(xcd * 128 + idx / NCB) * 128;
  const int  col0 = (idx % NCB) * 128;

  f32x4 acc[4][4];
#pragma unroll
  for (int m=0;m<4;m++)
#pragma unroll
    for (int n=0;n<4;n++) acc[m][n] = (f32x4){0.f,0.f,0.f,0.f};

  for (int kt = 0; kt < KD; kt += 64) {
    __syncthreads();
    if (MODE == 0) {
      const float* A = (const float*)Av;
#pragma unroll
      for (int i = 0; i < 8; i++) {
        int flat = i*256 + tid;
        int r = flat >> 4, c4 = flat & 15;
        const float4 v = *(const float4*)(A + (row0 + r)*KD + kt + c4*4);
        short4v pk;
        pk[0] = (short)f2bf(v.x); pk[1] = (short)f2bf(v.y);
        pk[2] = (short)f2bf(v.z); pk[3] = (short)f2bf(v.w);
        int addr = r*64 + (((c4>>1) ^ (r&7))<<3) + ((c4&1)<<2);
        *(short4v*)(As + addr) = pk;
      }
    } else {
      const short* A = (const short*)Av;
#pragma unroll
      for (int j = 0; j < 4; j++) {
        int f = j*256 + tid;               // 16B-chunk index
        int r = f >> 3, p = f & 7;
        const short* src = A + (row0 + r)*KD + kt + ((p ^ (r&7))<<3);
        gl_lds16(src, As + ((j*256 + (wid<<6))<<3));
      }
    }
    // B: global_load_lds with source-side XOR swizzle (LDS dest stays linear)
#pragma unroll
    for (int j = 0; j < 4; j++) {
      int f = j*256 + tid;
      int r = f >> 3, p = f & 7;
      const short* src = Bt + (long)(col0 + r)*KD + kt + ((p ^ (r&7))<<3);
      gl_lds16(src, Bs + ((j*256 + (wid<<6))<<3));
    }
    __syncthreads();
#pragma unroll
    for (int ks = 0; ks < 2; ks++) {
      short8 af[4], bfv[4];
#pragma unroll
      for (int m=0;m<4;m++){
        int r = wr*64 + m*16 + (lane & 15);
        int g = ks*4 + (lane >> 4);
        af[m] = *(const short8*)(As + r*64 + ((g ^ (r&7))<<3));
      }
#pragma unroll
      for (int n=0;n<4;n++){
        int r = wc*64 + n*16 + (lane & 15);
        int g = ks*4 + (lane >> 4);
        bfv[n] = *(const short8*)(Bs + r*64 + ((g ^ (r&7))<<3));
      }
#pragma unroll
      for (int m=0;m<4;m++)
#pragma unroll
        for (int n=0;n<4;n++)
          acc[m][n] = __builtin_amdgcn_mfma_f32_16x16x32_bf16(af[m], bfv[n], acc[m][n], 0, 0, 0);
    }
  }

  // epilogue. C/D frag layout: col=lane&15, row=(lane>>4)*4+reg
  if (MODE == 0) {
    // repack via LDS -> coalesced short8 stores
    float bcol[4];
#pragma unroll
    for (int n=0;n<4;n++){
      int col = col0 + wc*64 + n*16 + (lane&15);
      bcol[n] = (col < 256) ? bias[col] : 0.f;
    }
    __syncthreads();
#pragma unroll
    for (int m=0;m<4;m++){
#pragma unroll
      for (int n=0;n<4;n++){
        int col = wc*64 + n*16 + (lane&15);
        int cg = col >> 3;
#pragma unroll
        for (int rg=0;rg<4;rg++){
          int row = wr*64 + m*16 + ((lane>>4)<<2) + rg;
          smem[row*128 + ((cg ^ (row&7))<<3) + (col&7)] = (short)f2bf(acc[m][n][rg] + bcol[n]);
        }
      }
    }
    __syncthreads();
    int row = tid >> 1, ch = tid & 1;
    long grow = row0 + row;
#pragma unroll
    for (int j=0;j<8;j++){
      int cg = ch*8 + j;
      short8 v = *(const short8*)(smem + row*128 + ((cg ^ (row&7))<<3));
      int col = col0 + cg*8;
      if (col0 < 256) *(short8*)(out_q + grow*256 + col)        = v;
      else            *(short8*)(out_kv + grow*512 + (col-256)) = v;
    }
  } else {
#pragma unroll
    for (int m=0;m<4;m++){
      long rowb = row0 + wr*64 + m*16 + ((lane>>4)<<2);
#pragma unroll
      for (int n=0;n<4;n++){
        int col = col0 + wc*64 + n*16 + (lane&15);
#pragma unroll
        for (int rg=0;rg<4;rg++){
          out_f[(rowb+rg)*ND + col] = acc[m][n][rg] + bias[col];
        }
      }
    }
  }
}

// ---------------- depthwise 3x3 stride-2 conv + BN + v_bias ------------------
// in: kv_buf bf16 (8,128,128,512) -> out: kv_ds bf16 (8,64,64,512)
__global__ __launch_bounds__(256) void dwconv_kernel(const short* __restrict__ kv_buf,
    const float* __restrict__ dw_w, const float* __restrict__ gamma,
    const float* __restrict__ beta, const float* __restrict__ mean,
    const float* __restrict__ var, const float* __restrict__ v_bias,
    short* __restrict__ kv_ds)
{
  int bid = blockIdx.x;             // 8*64*8 = 4096
  int b = bid >> 9, rem = bid & 511;
  int y2 = rem >> 3, xb = rem & 7;
  int tid = threadIdx.x;
  int cg = tid & 31, xl = tid >> 5;
  int x2 = xb*8 + xl;
  int ch0 = cg*16;
  float acc[16];
#pragma unroll
  for (int i=0;i<16;i++) acc[i] = 0.f;
#pragma unroll
  for (int dy=0; dy<3; dy++){
    int y = y2*2 + dy;
    if (y >= 128) continue;
#pragma unroll
    for (int dx=0; dx<3; dx++){
      int x = x2*2 + dx;
      if (x >= 128) continue;
      const short* p = kv_buf + ((long)((b*128+y)*128 + x))*512 + ch0;
      short8 v0 = *(const short8*)p;
      short8 v1 = *(const short8*)(p+8);
      const float* wp = dw_w + (dy*3+dx)*512 + ch0;
#pragma unroll
      for (int i=0;i<8;i++) acc[i]   += bf2f((unsigned short)v0[i]) * wp[i];
#pragma unroll
      for (int i=0;i<8;i++) acc[8+i] += bf2f((unsigned short)v1[i]) * wp[8+i];
    }
  }
  short8 r0, r1;
#pragma unroll
  for (int i=0;i<16;i++){
    int c = ch0 + i;
    float r = (acc[i]-mean[c]) * rsqrtf(var[c]+1e-3f) * gamma[c] + beta[c];
    if (c >= 256) r += v_bias[c-256];
    if (i<8) r0[i] = (short)f2bf(r); else r1[i-8] = (short)f2bf(r);
  }
  short* o = kv_ds + ((long)((b*64+y2)*64 + x2))*512 + ch0;
  *(short8*)o = r0;
  *(short8*)(o+8) = r1;
}

// ---------------- halo attention --------------------------------------------
// grid: 2048 (= 8 batch * 256 windows); block: 256 (4 waves, each 2 heads)
__global__ __launch_bounds__(256) void halo_attn_kernel(const short* __restrict__ q_buf,
    const short* __restrict__ kv_ds, const float* __restrict__ relb,
    const float* __restrict__ scale, short* __restrict__ attn_out)
{
  __shared__ float qss[8][64];
  __shared__ float kss[8][64];
  __shared__ short vts[4][32][72];  // per-wave V^T [dim][key], 144B rows (16B aligned)
  __shared__ short ps [4][64][72];  // per-wave P   [query][key]

  const int bid = blockIdx.x;
  const int b = bid >> 8, wno = bid & 255;
  const int bi = wno >> 4, bj = wno & 15;
  const int tid = threadIdx.x;
  const int w = tid >> 6, lane = tid & 63;

  // ---- sum-of-squares prepass (for post-hoc l2 normalization) ----
#pragma unroll
  for (int i=0;i<4;i++){
    int idx = i*256 + tid;        // 0..1023: [0,512) q rows, [512,1024) k rows
    int isk = idx >> 9;
    int h   = (idx >> 6) & 7;
    int row = idx & 63;
    float ss = 0.f;
    if (!isk) {
      int qy = row>>3, qx = row&7;
      const short* p = q_buf + ((long)((b*128 + bi*8 + qy)*128 + (bj*8+qx)))*256 + h*32;
#pragma unroll
      for (int j=0;j<4;j++){
        short8 v = *(const short8*)(p + j*8);
#pragma unroll
        for (int e=0;e<8;e++){ float f = bf2f((unsigned short)v[e]); ss += f*f; }
      }
      qss[h][row] = fmaxf(ss, 1.55e-5f);
    } else {
      int ky = row>>3, kx = row&7;
      int yy = bi*4 - 2 + ky, xx = bj*4 - 2 + kx;
      if (yy>=0 && yy<64 && xx>=0 && xx<64) {
        const short* p = kv_ds + ((long)((b*64+yy)*64+xx))*512 + h*32;
#pragma unroll
        for (int j=0;j<4;j++){
          short8 v = *(const short8*)(p + j*8);
#pragma unroll
          for (int e=0;e<8;e++){ float f = bf2f((unsigned short)v[e]); ss += f*f; }
        }
      }
      kss[h][row] = fmaxf(ss, 1.55e-5f);
    }
  }
  __syncthreads();

  const short8 zero8 = {0,0,0,0,0,0,0,0};

  for (int hi=0; hi<2; hi++){
    int h = w + hi*4;
    float lscale = __expf(fminf(scale[h], 4.6051702f)); // exp(min(s, ln 100))

    // ---- stage V^T (per wave) ----
#pragma unroll 4
    for (int j=0;j<32;j++){
      int flat = j*64 + lane;
      int key = flat >> 5, d = flat & 31;
      int ky = key>>3, kx = key&7;
      int yy = bi*4-2+ky, xx = bj*4-2+kx;
      short val = 0;
      if (yy>=0 && yy<64 && xx>=0 && xx<64)
        val = kv_ds[((long)((b*64+yy)*64+xx))*512 + 256 + h*32 + d];
      vts[w][d][key] = val;
    }

    // ---- S^T = K * Q^T  (raw, unnormalized) ----
    short8 af[4], bfv[4];
#pragma unroll
    for (int m=0;m<4;m++){
      int key = m*16 + (lane&15);
      int ky = key>>3, kx = key&7;
      int yy = bi*4-2+ky, xx = bj*4-2+kx;
      if (yy>=0 && yy<64 && xx>=0 && xx<64)
        af[m] = *(const short8*)(kv_ds + ((long)((b*64+yy)*64+xx))*512 + h*32 + ((lane>>4)<<3));
      else
        af[m] = zero8;
    }
#pragma unroll
    for (int n=0;n<4;n++){
      int q = n*16 + (lane&15);
      int qy = q>>3, qx = q&7;
      bfv[n] = *(const short8*)(q_buf + ((long)((b*128+bi*8+qy)*128 + bj*8+qx))*256 + h*32 + ((lane>>4)<<3));
    }
    f32x4 sc_[4][4];
#pragma unroll
    for (int m=0;m<4;m++)
#pragma unroll
      for (int n=0;n<4;n++)
        sc_[m][n] = __builtin_amdgcn_mfma_f32_16x16x32_bf16(af[m], bfv[n],
                        (f32x4){0.f,0.f,0.f,0.f}, 0, 0, 0);

    // ---- logits: scale + rel bias + pad mask; key=m*16+(lane>>4)*4+reg, query=n*16+(lane&15)
    float rq[4];
#pragma unroll
    for (int n=0;n<4;n++) rq[n] = rsqrtf(qss[h][n*16 + (lane&15)]);
    float mx[4] = {-1e30f,-1e30f,-1e30f,-1e30f};
#pragma unroll
    for (int m=0;m<4;m++){
      int key0 = m*16 + ((lane>>4)<<2);
      float rk[4], mk[4];
#pragma unroll
      for (int r=0;r<4;r++){
        int key = key0 + r;
        int ky = key>>3, kx = key&7;
        int yy = bi*4-2+ky, xx = bj*4-2+kx;
        rk[r] = rsqrtf(kss[h][key]);
        mk[r] = (yy>=0 && yy<64 && xx>=0 && xx<64) ? 0.f : -100.f;
      }
#pragma unroll
      for (int n=0;n<4;n++){
        int q = n*16 + (lane&15);
        f32x4 rb = *(const f32x4*)(relb + h*4096 + q*64 + key0);
#pragma unroll
        for (int r=0;r<4;r++){
          float v = sc_[m][n][r] * (rk[r]*rq[n]*lscale) + rb[r] + mk[r];
          sc_[m][n][r] = v;
          mx[n] = fmaxf(mx[n], v);
        }
      }
    }
#pragma unroll
    for (int n=0;n<4;n++){
      mx[n] = fmaxf(mx[n], __shfl_xor(mx[n], 16));
      mx[n] = fmaxf(mx[n], __shfl_xor(mx[n], 32));
    }
    float sm[4] = {0.f,0.f,0.f,0.f};
#pragma unroll
    for (int m=0;m<4;m++)
#pragma unroll
      for (int n=0;n<4;n++)
#pragma unroll
        for (int r=0;r<4;r++){
          float e = __expf(sc_[m][n][r] - mx[n]);
          sc_[m][n][r] = e;
          sm[n] += e;
        }
#pragma unroll
    for (int n=0;n<4;n++){
      sm[n] += __shfl_xor(sm[n], 16);
      sm[n] += __shfl_xor(sm[n], 32);
      sm[n] = 1.f / sm[n];
    }
    // ---- write P[query][key] (consecutive regs are consecutive keys -> b64) ----
#pragma unroll
    for (int n=0;n<4;n++){
      int q = n*16 + (lane&15);
#pragma unroll
      for (int m=0;m<4;m++){
        short4v pk;
#pragma unroll
        for (int r=0;r<4;r++) pk[r] = (short)f2bf(sc_[m][n][r] * sm[n]);
        *(short4v*)(&ps[w][q][m*16 + ((lane>>4)<<2)]) = pk;
      }
    }
    __syncthreads();

    // ---- O = P * V ----
    f32x4 oc[4][2];
#pragma unroll
    for (int m=0;m<4;m++)
#pragma unroll
      for (int n=0;n<2;n++) oc[m][n] = (f32x4){0.f,0.f,0.f,0.f};
#pragma unroll
    for (int ks=0; ks<2; ks++){
      short8 pa[4], vb[2];
#pragma unroll
      for (int m=0;m<4;m++)
        pa[m] = *(const short8*)(&ps[w][m*16 + (lane&15)][ks*32 + ((lane>>4)<<3)]);
#pragma unroll
      for (int n=0;n<2;n++)
        vb[n] = *(const short8*)(&vts[w][n*16 + (lane&15)][ks*32 + ((lane>>4)<<3)]);
#pragma unroll
      for (int m=0;m<4;m++)
#pragma unroll
        for (int n=0;n<2;n++)
          oc[m][n] = __builtin_amdgcn_mfma_f32_16x16x32_bf16(pa[m], vb[n], oc[m][n], 0, 0, 0);
    }
    // ---- store: query=m*16+(lane>>4)*4+reg, dim=n*16+(lane&15) ----
#pragma unroll
    for (int m=0;m<4;m++){
      int q0 = m*16 + ((lane>>4)<<2);
#pragma unroll
      for (int n=0;n<2;n++){
        int d = n*16 + (lane&15);
#pragma unroll
        for (int r=0;r<4;r++){
          int q = q0 + r;
          int qy = q>>3, qx = q&7;
          attn_out[((long)((b*128 + bi*8+qy)*128 + bj*8+qx))*256 + h*32 + d] =
              (short)f2bf(oc[m][n][r]);
        }
      }
    }
    __syncthreads();
  }
}

// ---------------- launch -----------------------------------------------------
extern "C" void kernel_launch(void* const* d_in, const int* in_sizes, int n_in,
                              void* d_out, int out_size, void* d_ws, size_t ws_size,
                              hipStream_t stream)
{
  (void)in_sizes; (void)n_in; (void)out_size; (void)ws_size;
  const float* inputs = (const float*)d_in[0];
  const float* qkv_w  = (const float*)d_in[1];
  const float* q_bias = (const float*)d_in[2];
  const float* v_bias = (const float*)d_in[3];
  const float* dw_w   = (const float*)d_in[4];
  const float* dw_g   = (const float*)d_in[5];
  const float* dw_b   = (const float*)d_in[6];
  const float* dw_m   = (const float*)d_in[7];
  const float* dw_v   = (const float*)d_in[8];
  const float* scale  = (const float*)d_in[9];
  const float* cpb_w1 = (const float*)d_in[10];
  const float* cpb_b1 = (const float*)d_in[11];
  const float* cpb_w2 = (const float*)d_in[12];
  const float* proj_w = (const float*)d_in[13];
  const float* proj_b = (const float*)d_in[14];

  char* ws = (char*)d_ws;
  short* q_buf    = (short*)(ws);                  //  64 MiB  (131072 x 256 bf16)
  short* kv_buf   = (short*)(ws + 67108864L);      // 128 MiB  (131072 x 512 bf16)
  short* kv_ds    = (short*)(ws + 201326592L);     //  32 MiB  (8x64x64x512 bf16)
  short* attn_buf = (short*)(ws + 234881024L);     //  64 MiB  (131072 x 256 bf16)
  short* qkvw_t   = (short*)(ws + 301989888L);     // 384 KiB  (768 x 256 bf16)
  short* projw_t  = (short*)(ws + 302383104L);     // 128 KiB  (256 x 256 bf16)
  float* relb     = (float*)(ws + 302514176L);     // 128 KiB  (8 x 64 x 64 f32)

  transpose_w_kernel<<<768, 256, 0, stream>>>(qkv_w, qkvw_t, 256, 768);
  transpose_w_kernel<<<256, 256, 0, stream>>>(proj_w, projw_t, 256, 256);
  relbias_kernel<<<64, 64, 0, stream>>>(cpb_w1, cpb_b1, cpb_w2, relb);

  gemm_bt_kernel<256, 768, 0><<<6144, 256, 0, stream>>>(
      inputs, qkvw_t, q_bias, q_buf, kv_buf, nullptr);

  dwconv_kernel<<<4096, 256, 0, stream>>>(kv_buf, dw_g ? dw_w : dw_w, dw_g, dw_b, dw_m, dw_v, v_bias, kv_ds);

  halo_attn_kernel<<<2048, 256, 0, stream>>>(q_buf, kv_ds, relb, scale, attn_buf);

  gemm_bt_kernel<256, 256, 1><<<2048, 256, 0, stream>>>(
      attn_buf, projw_t, proj_b, nullptr, nullptr, (float*)d_out);
}

// Round 3
// 580.639 us; speedup vs baseline: 1.0899x; 1.0200x over previous
//
#include <hip/hip_runtime.h>
#include <stdint.h>

// Problem constants
// B=8, H=128, W=128, C=256, HEADS=8, WIN=8, HALO=8, BLOCK=4, PAD=2
// QK_U=32, QK_CH=256, KV_CH=512, M = 8*128*128 = 131072

typedef __attribute__((ext_vector_type(8))) short short8;
typedef __attribute__((ext_vector_type(4))) short short4v;
typedef __attribute__((ext_vector_type(4))) float f32x4;

__device__ __forceinline__ float bf2f(unsigned short u){
  union { unsigned int i; float f; } x; x.i = ((unsigned int)u)<<16; return x.f;
}
__device__ __forceinline__ unsigned short f2bf(float f){
  union { float f; unsigned int i; } x; x.f = f;
  unsigned int r = x.i + 0x7FFFu + ((x.i>>16)&1u);
  return (unsigned short)(r>>16);
}
__device__ __forceinline__ void gl_lds16(const void* g, void* l){
  __builtin_amdgcn_global_load_lds((const __attribute__((address_space(1))) unsigned int*)g,
                                   (__attribute__((address_space(3))) unsigned int*)l, 16, 0, 0);
}

// ---------------- f32 -> bf16 streaming convert ------------------------------
__global__ __launch_bounds__(256) void cvt_bf16_kernel(const float* __restrict__ in,
                                                       short* __restrict__ out, long n8)
{
  long stride = (long)gridDim.x * 256;
  for (long i = (long)blockIdx.x*256 + threadIdx.x; i < n8; i += stride){
    float4 a = ((const float4*)in)[2*i];
    float4 b = ((const float4*)in)[2*i+1];
    short8 v;
    v[0]=(short)f2bf(a.x); v[1]=(short)f2bf(a.y); v[2]=(short)f2bf(a.z); v[3]=(short)f2bf(a.w);
    v[4]=(short)f2bf(b.x); v[5]=(short)f2bf(b.y); v[6]=(short)f2bf(b.z); v[7]=(short)f2bf(b.w);
    ((short8*)out)[i] = v;
  }
}

// ---------------- weight transpose + bf16 convert: wt[n][k] = w[k][n] --------
__global__ void transpose_w_kernel(const float* __restrict__ w, short* __restrict__ wt,
                                   int K, int N)
{
  int idx = blockIdx.x*256 + threadIdx.x;
  if (idx >= K*N) return;
  int n = idx / K, k = idx - n*K;
  wt[idx] = (short)f2bf(w[(long)k*N + n]);
}

// ---------------- relative position bias table: out[8][64][64] --------------
__global__ __launch_bounds__(64) void relbias_kernel(const float* __restrict__ w1,
    const float* __restrict__ b1, const float* __restrict__ w2, float* __restrict__ out)
{
  int q = blockIdx.x;   // 0..63  (qy*8+qx)
  int k = threadIdx.x;  // 0..63  (ky*8+kx)
  float ry = (float)(q>>3) - (((float)(k>>3) - 2.f)*2.f + 0.5f);
  float rx = (float)(q&7)  - (((float)(k&7)  - 2.f)*2.f + 0.5f);
  ry *= (8.f/7.f); rx *= (8.f/7.f);
  float sy = (ry>0.f)?1.f:((ry<0.f)?-1.f:0.f);
  float sx = (rx>0.f)?1.f:((rx<0.f)?-1.f:0.f);
  ry = sy * log2f(fabsf(ry)+1.f) * (1.f/3.f);
  rx = sx * log2f(fabsf(rx)+1.f) * (1.f/3.f);
  float acc[8] = {0,0,0,0,0,0,0,0};
  for (int j=0;j<512;j++){
    float hm = ry*w1[j] + rx*w1[512+j] + b1[j];
    hm = fmaxf(hm, 0.f);
#pragma unroll
    for (int h=0;h<8;h++) acc[h] += hm * w2[j*8+h];
  }
#pragma unroll
  for (int h=0;h<8;h++)
    out[h*4096 + q*64 + k] = 16.f / (1.f + __expf(-acc[h]));
}

// ---------------- GEMM: C[M x ND] = A[M x KD=256] * Bt[ND x 256]^T -----------
// A is bf16. Double-buffered LDS (2x32KB), global_load_lds staging with
// source-side XOR swizzle, bijective XCD swizzle (col blocks of a row block
// run consecutively on the same XCD).
// OUTMODE 0: split cols: col<256 -> out_q (+bias), else -> out_kv (bf16)
// OUTMODE 1: out_f = val + bias[col] (f32), coalesced via LDS repack
template<int ND, int OUTMODE>
__global__ __launch_bounds__(256) void gemm_bt_kernel(const short* __restrict__ A,
    const short* __restrict__ Bt, const float* __restrict__ bias,
    short* __restrict__ out_q, short* __restrict__ out_kv, float* __restrict__ out_f)
{
  __shared__ short smem[32768];   // As0 | As1 | Bs0 | Bs1, 16KB each
  const int tid  = threadIdx.x;
  const int lane = tid & 63;
  const int wid  = tid >> 6;
  const int wr = wid >> 1, wc = wid & 1;

  constexpr int NCB = ND / 128;
  const int bid = blockIdx.x;
  const int xcd = bid & 7;
  const int idx = bid >> 3;
  const long row0 = (long)(xcd * 128 + idx / NCB) * 128;   // 1024 row blocks total
  const int  col0 = (idx % NCB) * 128;

  f32x4 acc[4][4];
#pragma unroll
  for (int m=0;m<4;m++)
#pragma unroll
    for (int n=0;n<4;n++) acc[m][n] = (f32x4){0.f,0.f,0.f,0.f};

  auto stage = [&](int buf, int kt){
#pragma unroll
    for (int j = 0; j < 4; j++) {
      int f = j*256 + tid;               // 16B-chunk index
      int r = f >> 3, p = f & 7;
      gl_lds16(A + (row0 + r)*256 + kt + ((p ^ (r&7))<<3),
               smem + buf*8192 + ((j*256 + (wid<<6))<<3));
      gl_lds16(Bt + (long)(col0 + r)*256 + kt + ((p ^ (r&7))<<3),
               smem + 16384 + buf*8192 + ((j*256 + (wid<<6))<<3));
    }
  };
  auto compute = [&](int buf){
    const short* As = smem + buf*8192;
    const short* Bs = smem + 16384 + buf*8192;
#pragma unroll
    for (int ks = 0; ks < 2; ks++) {
      short8 af[4], bfv[4];
#pragma unroll
      for (int m=0;m<4;m++){
        int r = wr*64 + m*16 + (lane & 15);
        int g = ks*4 + (lane >> 4);
        af[m] = *(const short8*)(As + r*64 + ((g ^ (r&7))<<3));
      }
#pragma unroll
      for (int n=0;n<4;n++){
        int r = wc*64 + n*16 + (lane & 15);
        int g = ks*4 + (lane >> 4);
        bfv[n] = *(const short8*)(Bs + r*64 + ((g ^ (r&7))<<3));
      }
#pragma unroll
      for (int m=0;m<4;m++)
#pragma unroll
        for (int n=0;n<4;n++)
          acc[m][n] = __builtin_amdgcn_mfma_f32_16x16x32_bf16(af[m], bfv[n], acc[m][n], 0, 0, 0);
    }
  };

  // 2-phase pipeline: stage(next) -> compute(cur) -> barrier (prefetch lands
  // under the compute, not cold).
  stage(0, 0);
  __syncthreads();
#pragma unroll
  for (int t = 0; t < 4; t++){
    if (t < 3) stage((t+1)&1, (t+1)*64);
    compute(t&1);
    __syncthreads();
  }

  // epilogue. C/D frag layout: col=lane&15, row=(lane>>4)*4+reg
  if (OUTMODE == 0) {
    float bcol[4];
#pragma unroll
    for (int n=0;n<4;n++){
      int col = col0 + wc*64 + n*16 + (lane&15);
      bcol[n] = (col < 256) ? bias[col] : 0.f;
    }
#pragma unroll
    for (int m=0;m<4;m++){
#pragma unroll
      for (int n=0;n<4;n++){
        int col = wc*64 + n*16 + (lane&15);
        int cg = col >> 3;
#pragma unroll
        for (int rg=0;rg<4;rg++){
          int row = wr*64 + m*16 + ((lane>>4)<<2) + rg;
          smem[row*128 + ((cg ^ (row&7))<<3) + (col&7)] = (short)f2bf(acc[m][n][rg] + bcol[n]);
        }
      }
    }
    __syncthreads();
    int row = tid >> 1, ch = tid & 1;
    long grow = row0 + row;
#pragma unroll
    for (int j=0;j<8;j++){
      int cg = ch*8 + j;
      short8 v = *(const short8*)(smem + row*128 + ((cg ^ (row&7))<<3));
      int col = col0 + cg*8;
      if (col0 < 256) *(short8*)(out_q + grow*256 + col)        = v;
      else            *(short8*)(out_kv + grow*512 + (col-256)) = v;
    }
  } else {
    float* fs = (float*)smem;
#pragma unroll
    for (int m=0;m<4;m++){
#pragma unroll
      for (int n=0;n<4;n++){
        int col = wc*64 + n*16 + (lane&15);
        int c4 = col >> 2;
        float bv = bias[col0 + col];
#pragma unroll
        for (int rg=0;rg<4;rg++){
          int row = wr*64 + m*16 + ((lane>>4)<<2) + rg;
          fs[row*128 + ((c4 ^ (row&7))<<2) + (col&3)] = acc[m][n][rg] + bv;
        }
      }
    }
    __syncthreads();
    int row = tid >> 1;
    long grow = row0 + row;
#pragma unroll
    for (int j=0;j<16;j++){
      int c4 = (tid&1)*16 + j;
      float4 v = *(const float4*)(fs + row*128 + ((c4 ^ (row&7))<<2));
      *(float4*)(out_f + grow*ND + col0 + c4*4) = v;
    }
  }
}

// ---------------- depthwise 3x3 stride-2 conv + BN + v_bias ------------------
// in: kv_buf bf16 (8,128,128,512) -> out: kv_ds bf16 (8,64,64,512)
__global__ __launch_bounds__(256) void dwconv_kernel(const short* __restrict__ kv_buf,
    const float* __restrict__ dw_w, const float* __restrict__ gamma,
    const float* __restrict__ beta, const float* __restrict__ mean,
    const float* __restrict__ var, const float* __restrict__ v_bias,
    short* __restrict__ kv_ds)
{
  int bid = blockIdx.x;             // 8*64*8 = 4096
  int b = bid >> 9, rem = bid & 511;
  int y2 = rem >> 3, xb = rem & 7;
  int tid = threadIdx.x;
  int cg = tid & 31, xl = tid >> 5;
  int x2 = xb*8 + xl;
  int ch0 = cg*16;
  float acc[16];
#pragma unroll
  for (int i=0;i<16;i++) acc[i] = 0.f;
#pragma unroll
  for (int dy=0; dy<3; dy++){
    int y = y2*2 + dy;
    if (y >= 128) continue;
#pragma unroll
    for (int dx=0; dx<3; dx++){
      int x = x2*2 + dx;
      if (x >= 128) continue;
      const short* p = kv_buf + ((long)((b*128+y)*128 + x))*512 + ch0;
      short8 v0 = *(const short8*)p;
      short8 v1 = *(const short8*)(p+8);
      const float* wp = dw_w + (dy*3+dx)*512 + ch0;
#pragma unroll
      for (int i=0;i<8;i++) acc[i]   += bf2f((unsigned short)v0[i]) * wp[i];
#pragma unroll
      for (int i=0;i<8;i++) acc[8+i] += bf2f((unsigned short)v1[i]) * wp[8+i];
    }
  }
  short8 r0, r1;
#pragma unroll
  for (int i=0;i<16;i++){
    int c = ch0 + i;
    float r = (acc[i]-mean[c]) * rsqrtf(var[c]+1e-3f) * gamma[c] + beta[c];
    if (c >= 256) r += v_bias[c-256];
    if (i<8) r0[i] = (short)f2bf(r); else r1[i-8] = (short)f2bf(r);
  }
  short* o = kv_ds + ((long)((b*64+y2)*64 + x2))*512 + ch0;
  *(short8*)o = r0;
  *(short8*)(o+8) = r1;
}

// ---------------- halo attention --------------------------------------------
// grid: 2048 (= 8 batch * 256 windows); block: 256 (4 waves, each 2 heads)
__global__ __launch_bounds__(256) void halo_attn_kernel(const short* __restrict__ q_buf,
    const short* __restrict__ kv_ds, const float* __restrict__ relb,
    const float* __restrict__ scale, short* __restrict__ attn_out)
{
  __shared__ float qss[8][64];
  __shared__ float kss[8][64];
  __shared__ short vts[4][32][72];  // per-wave V^T [dim][key], 144B rows (16B aligned)
  __shared__ short ps [4][64][72];  // per-wave P   [query][key]

  const int bid = blockIdx.x;
  const int b = bid >> 8, wno = bid & 255;
  const int bi = wno >> 4, bj = wno & 15;
  const int tid = threadIdx.x;
  const int w = tid >> 6, lane = tid & 63;

  // ---- sum-of-squares prepass (for post-hoc l2 normalization) ----
#pragma unroll
  for (int i=0;i<4;i++){
    int idx = i*256 + tid;        // 0..1023: [0,512) q rows, [512,1024) k rows
    int isk = idx >> 9;
    int h   = (idx >> 6) & 7;
    int row = idx & 63;
    float ss = 0.f;
    if (!isk) {
      int qy = row>>3, qx = row&7;
      const short* p = q_buf + ((long)((b*128 + bi*8 + qy)*128 + (bj*8+qx)))*256 + h*32;
#pragma unroll
      for (int j=0;j<4;j++){
        short8 v = *(const short8*)(p + j*8);
#pragma unroll
        for (int e=0;e<8;e++){ float f = bf2f((unsigned short)v[e]); ss += f*f; }
      }
      qss[h][row] = fmaxf(ss, 1.55e-5f);
    } else {
      int ky = row>>3, kx = row&7;
      int yy = bi*4 - 2 + ky, xx = bj*4 - 2 + kx;
      if (yy>=0 && yy<64 && xx>=0 && xx<64) {
        const short* p = kv_ds + ((long)((b*64+yy)*64+xx))*512 + h*32;
#pragma unroll
        for (int j=0;j<4;j++){
          short8 v = *(const short8*)(p + j*8);
#pragma unroll
          for (int e=0;e<8;e++){ float f = bf2f((unsigned short)v[e]); ss += f*f; }
        }
      }
      kss[h][row] = fmaxf(ss, 1.55e-5f);
    }
  }
  __syncthreads();

  const short8 zero8 = {0,0,0,0,0,0,0,0};

  for (int hi=0; hi<2; hi++){
    int h = w + hi*4;
    float lscale = __expf(fminf(scale[h], 4.6051702f)); // exp(min(s, ln 100))

    // ---- stage V^T (per wave) ----
#pragma unroll 4
    for (int j=0;j<32;j++){
      int flat = j*64 + lane;
      int key = flat >> 5, d = flat & 31;
      int ky = key>>3, kx = key&7;
      int yy = bi*4-2+ky, xx = bj*4-2+kx;
      short val = 0;
      if (yy>=0 && yy<64 && xx>=0 && xx<64)
        val = kv_ds[((long)((b*64+yy)*64+xx))*512 + 256 + h*32 + d];
      vts[w][d][key] = val;
    }

    // ---- S^T = K * Q^T  (raw, unnormalized) ----
    short8 af[4], bfv[4];
#pragma unroll
    for (int m=0;m<4;m++){
      int key = m*16 + (lane&15);
      int ky = key>>3, kx = key&7;
      int yy = bi*4-2+ky, xx = bj*4-2+kx;
      if (yy>=0 && yy<64 && xx>=0 && xx<64)
        af[m] = *(const short8*)(kv_ds + ((long)((b*64+yy)*64+xx))*512 + h*32 + ((lane>>4)<<3));
      else
        af[m] = zero8;
    }
#pragma unroll
    for (int n=0;n<4;n++){
      int q = n*16 + (lane&15);
      int qy = q>>3, qx = q&7;
      bfv[n] = *(const short8*)(q_buf + ((long)((b*128+bi*8+qy)*128 + bj*8+qx))*256 + h*32 + ((lane>>4)<<3));
    }
    f32x4 sc_[4][4];
#pragma unroll
    for (int m=0;m<4;m++)
#pragma unroll
      for (int n=0;n<4;n++)
        sc_[m][n] = __builtin_amdgcn_mfma_f32_16x16x32_bf16(af[m], bfv[n],
                        (f32x4){0.f,0.f,0.f,0.f}, 0, 0, 0);

    // ---- logits: scale + rel bias + pad mask; key=m*16+(lane>>4)*4+reg, query=n*16+(lane&15)
    float rq[4];
#pragma unroll
    for (int n=0;n<4;n++) rq[n] = rsqrtf(qss[h][n*16 + (lane&15)]);
    float mx[4] = {-1e30f,-1e30f,-1e30f,-1e30f};
#pragma unroll
    for (int m=0;m<4;m++){
      int key0 = m*16 + ((lane>>4)<<2);
      float rk[4], mk[4];
#pragma unroll
      for (int r=0;r<4;r++){
        int key = key0 + r;
        int ky = key>>3, kx = key&7;
        int yy = bi*4-2+ky, xx = bj*4-2+kx;
        rk[r] = rsqrtf(kss[h][key]);
        mk[r] = (yy>=0 && yy<64 && xx>=0 && xx<64) ? 0.f : -100.f;
      }
#pragma unroll
      for (int n=0;n<4;n++){
        int q = n*16 + (lane&15);
        f32x4 rb = *(const f32x4*)(relb + h*4096 + q*64 + key0);
#pragma unroll
        for (int r=0;r<4;r++){
          float v = sc_[m][n][r] * (rk[r]*rq[n]*lscale) + rb[r] + mk[r];
          sc_[m][n][r] = v;
          mx[n] = fmaxf(mx[n], v);
        }
      }
    }
#pragma unroll
    for (int n=0;n<4;n++){
      mx[n] = fmaxf(mx[n], __shfl_xor(mx[n], 16));
      mx[n] = fmaxf(mx[n], __shfl_xor(mx[n], 32));
    }
    float sm[4] = {0.f,0.f,0.f,0.f};
#pragma unroll
    for (int m=0;m<4;m++)
#pragma unroll
      for (int n=0;n<4;n++)
#pragma unroll
        for (int r=0;r<4;r++){
          float e = __expf(sc_[m][n][r] - mx[n]);
          sc_[m][n][r] = e;
          sm[n] += e;
        }
#pragma unroll
    for (int n=0;n<4;n++){
      sm[n] += __shfl_xor(sm[n], 16);
      sm[n] += __shfl_xor(sm[n], 32);
      sm[n] = 1.f / sm[n];
    }
    // ---- write P[query][key] (consecutive regs are consecutive keys -> b64) ----
#pragma unroll
    for (int n=0;n<4;n++){
      int q = n*16 + (lane&15);
#pragma unroll
      for (int m=0;m<4;m++){
        short4v pk;
#pragma unroll
        for (int r=0;r<4;r++) pk[r] = (short)f2bf(sc_[m][n][r] * sm[n]);
        *(short4v*)(&ps[w][q][m*16 + ((lane>>4)<<2)]) = pk;
      }
    }
    __syncthreads();

    // ---- O = P * V ----
    f32x4 oc[4][2];
#pragma unroll
    for (int m=0;m<4;m++)
#pragma unroll
      for (int n=0;n<2;n++) oc[m][n] = (f32x4){0.f,0.f,0.f,0.f};
#pragma unroll
    for (int ks=0; ks<2; ks++){
      short8 pa[4], vb[2];
#pragma unroll
      for (int m=0;m<4;m++)
        pa[m] = *(const short8*)(&ps[w][m*16 + (lane&15)][ks*32 + ((lane>>4)<<3)]);
#pragma unroll
      for (int n=0;n<2;n++)
        vb[n] = *(const short8*)(&vts[w][n*16 + (lane&15)][ks*32 + ((lane>>4)<<3)]);
#pragma unroll
      for (int m=0;m<4;m++)
#pragma unroll
        for (int n=0;n<2;n++)
          oc[m][n] = __builtin_amdgcn_mfma_f32_16x16x32_bf16(pa[m], vb[n], oc[m][n], 0, 0, 0);
    }
    // ---- store: query=m*16+(lane>>4)*4+reg, dim=n*16+(lane&15) ----
#pragma unroll
    for (int m=0;m<4;m++){
      int q0 = m*16 + ((lane>>4)<<2);
#pragma unroll
      for (int n=0;n<2;n++){
        int d = n*16 + (lane&15);
#pragma unroll
        for (int r=0;r<4;r++){
          int q = q0 + r;
          int qy = q>>3, qx = q&7;
          attn_out[((long)((b*128 + bi*8+qy)*128 + bj*8+qx))*256 + h*32 + d] =
              (short)f2bf(oc[m][n][r]);
        }
      }
    }
    __syncthreads();
  }
}

// ---------------- launch -----------------------------------------------------
extern "C" void kernel_launch(void* const* d_in, const int* in_sizes, int n_in,
                              void* d_out, int out_size, void* d_ws, size_t ws_size,
                              hipStream_t stream)
{
  (void)in_sizes; (void)n_in; (void)out_size; (void)ws_size;
  const float* inputs = (const float*)d_in[0];
  const float* qkv_w  = (const float*)d_in[1];
  const float* q_bias = (const float*)d_in[2];
  const float* v_bias = (const float*)d_in[3];
  const float* dw_w   = (const float*)d_in[4];
  const float* dw_g   = (const float*)d_in[5];
  const float* dw_b   = (const float*)d_in[6];
  const float* dw_m   = (const float*)d_in[7];
  const float* dw_v   = (const float*)d_in[8];
  const float* scale  = (const float*)d_in[9];
  const float* cpb_w1 = (const float*)d_in[10];
  const float* cpb_b1 = (const float*)d_in[11];
  const float* cpb_w2 = (const float*)d_in[12];
  const float* proj_w = (const float*)d_in[13];
  const float* proj_b = (const float*)d_in[14];

  char* ws = (char*)d_ws;
  short* q_buf    = (short*)(ws);                  //  64 MiB  (131072 x 256 bf16)
  short* kv_buf   = (short*)(ws + 67108864L);      // 128 MiB  (131072 x 512 bf16)
  short* kv_ds    = (short*)(ws + 201326592L);     //  32 MiB  (8x64x64x512 bf16)
  short* attn_buf = (short*)(ws + 234881024L);     //  64 MiB  (131072 x 256 bf16)
  short* qkvw_t   = (short*)(ws + 301989888L);     // 384 KiB  (768 x 256 bf16)
  short* projw_t  = (short*)(ws + 302383104L);     // 128 KiB  (256 x 256 bf16)
  float* relb     = (float*)(ws + 302514176L);     // 128 KiB  (8 x 64 x 64 f32)

  // a_bf reuses the attn_buf region (dead until the attention kernel runs,
  // and a_bf is dead before attention writes it).
  short* a_bf = attn_buf;

  cvt_bf16_kernel<<<2048, 256, 0, stream>>>(inputs, a_bf, 4194304L);
  transpose_w_kernel<<<768, 256, 0, stream>>>(qkv_w, qkvw_t, 256, 768);
  transpose_w_kernel<<<256, 256, 0, stream>>>(proj_w, projw_t, 256, 256);
  relbias_kernel<<<64, 64, 0, stream>>>(cpb_w1, cpb_b1, cpb_w2, relb);

  gemm_bt_kernel<768, 0><<<6144, 256, 0, stream>>>(
      a_bf, qkvw_t, q_bias, q_buf, kv_buf, nullptr);

  dwconv_kernel<<<4096, 256, 0, stream>>>(kv_buf, dw_w, dw_g, dw_b, dw_m, dw_v, v_bias, kv_ds);

  halo_attn_kernel<<<2048, 256, 0, stream>>>(q_buf, kv_ds, relb, scale, attn_buf);

  gemm_bt_kernel<256, 1><<<2048, 256, 0, stream>>>(
      attn_buf, projw_t, proj_b, nullptr, nullptr, (float*)d_out);
}

// Round 4
// 454.624 us; speedup vs baseline: 1.3920x; 1.2772x over previous
//
#include <hip/hip_runtime.h>
#include <stdint.h>

// Problem constants
// B=8, H=128, W=128, C=256, HEADS=8, WIN=8, HALO=8, BLOCK=4, PAD=2
// QK_U=32, QK_CH=256, KV_CH=512, M = 8*128*128 = 131072

typedef __attribute__((ext_vector_type(8))) short short8;
typedef __attribute__((ext_vector_type(4))) short short4v;
typedef __attribute__((ext_vector_type(4))) float f32x4;

__device__ __forceinline__ float bf2f(unsigned short u){
  union { unsigned int i; float f; } x; x.i = ((unsigned int)u)<<16; return x.f;
}
__device__ __forceinline__ unsigned short f2bf(float f){
  union { float f; unsigned int i; } x; x.f = f;
  unsigned int r = x.i + 0x7FFFu + ((x.i>>16)&1u);
  return (unsigned short)(r>>16);
}
__device__ __forceinline__ void gl_lds16(const void* g, void* l){
  __builtin_amdgcn_global_load_lds((const __attribute__((address_space(1))) unsigned int*)g,
                                   (__attribute__((address_space(3))) unsigned int*)l, 16, 0, 0);
}

// ---------------- f32 -> bf16 streaming convert ------------------------------
__global__ __launch_bounds__(256) void cvt_bf16_kernel(const float* __restrict__ in,
                                                       short* __restrict__ out, long n8)
{
  long stride = (long)gridDim.x * 256;
  for (long i = (long)blockIdx.x*256 + threadIdx.x; i < n8; i += stride){
    float4 a = ((const float4*)in)[2*i];
    float4 b = ((const float4*)in)[2*i+1];
    short8 v;
    v[0]=(short)f2bf(a.x); v[1]=(short)f2bf(a.y); v[2]=(short)f2bf(a.z); v[3]=(short)f2bf(a.w);
    v[4]=(short)f2bf(b.x); v[5]=(short)f2bf(b.y); v[6]=(short)f2bf(b.z); v[7]=(short)f2bf(b.w);
    ((short8*)out)[i] = v;
  }
}

// ---------------- weight transpose + bf16 convert: wt[n][k] = w[k][n] --------
__global__ void transpose_w_kernel(const float* __restrict__ w, short* __restrict__ wt,
                                   int K, int N)
{
  int idx = blockIdx.x*256 + threadIdx.x;
  if (idx >= K*N) return;
  int n = idx / K, k = idx - n*K;
  wt[idx] = (short)f2bf(w[(long)k*N + n]);
}

// ---------------- relative position bias table: out[8][64][64] --------------
__global__ __launch_bounds__(64) void relbias_kernel(const float* __restrict__ w1,
    const float* __restrict__ b1, const float* __restrict__ w2, float* __restrict__ out)
{
  int q = blockIdx.x;   // 0..63  (qy*8+qx)
  int k = threadIdx.x;  // 0..63  (ky*8+kx)
  float ry = (float)(q>>3) - (((float)(k>>3) - 2.f)*2.f + 0.5f);
  float rx = (float)(q&7)  - (((float)(k&7)  - 2.f)*2.f + 0.5f);
  ry *= (8.f/7.f); rx *= (8.f/7.f);
  float sy = (ry>0.f)?1.f:((ry<0.f)?-1.f:0.f);
  float sx = (rx>0.f)?1.f:((rx<0.f)?-1.f:0.f);
  ry = sy * log2f(fabsf(ry)+1.f) * (1.f/3.f);
  rx = sx * log2f(fabsf(rx)+1.f) * (1.f/3.f);
  float acc[8] = {0,0,0,0,0,0,0,0};
  for (int j=0;j<512;j++){
    float hm = ry*w1[j] + rx*w1[512+j] + b1[j];
    hm = fmaxf(hm, 0.f);
#pragma unroll
    for (int h=0;h<8;h++) acc[h] += hm * w2[j*8+h];
  }
#pragma unroll
  for (int h=0;h<8;h++)
    out[h*4096 + q*64 + k] = 16.f / (1.f + __expf(-acc[h]));
}

// ---------------- GEMM: C[M x ND] = A[M x KD=256] * Bt[ND x 256]^T -----------
template<int ND, int OUTMODE>
__global__ __launch_bounds__(256) void gemm_bt_kernel(const short* __restrict__ A,
    const short* __restrict__ Bt, const float* __restrict__ bias,
    short* __restrict__ out_q, short* __restrict__ out_kv, float* __restrict__ out_f)
{
  __shared__ short smem[32768];   // As0 | As1 | Bs0 | Bs1, 16KB each
  const int tid  = threadIdx.x;
  const int lane = tid & 63;
  const int wid  = tid >> 6;
  const int wr = wid >> 1, wc = wid & 1;

  constexpr int NCB = ND / 128;
  const int bid = blockIdx.x;
  const int xcd = bid & 7;
  const int idx = bid >> 3;
  const long row0 = (long)(xcd * 128 + idx / NCB) * 128;
  const int  col0 = (idx % NCB) * 128;

  f32x4 acc[4][4];
#pragma unroll
  for (int m=0;m<4;m++)
#pragma unroll
    for (int n=0;n<4;n++) acc[m][n] = (f32x4){0.f,0.f,0.f,0.f};

  auto stage = [&](int buf, int kt){
#pragma unroll
    for (int j = 0; j < 4; j++) {
      int f = j*256 + tid;               // 16B-chunk index
      int r = f >> 3, p = f & 7;
      gl_lds16(A + (row0 + r)*256 + kt + ((p ^ (r&7))<<3),
               smem + buf*8192 + ((j*256 + (wid<<6))<<3));
      gl_lds16(Bt + (long)(col0 + r)*256 + kt + ((p ^ (r&7))<<3),
               smem + 16384 + buf*8192 + ((j*256 + (wid<<6))<<3));
    }
  };
  auto compute = [&](int buf){
    const short* As = smem + buf*8192;
    const short* Bs = smem + 16384 + buf*8192;
#pragma unroll
    for (int ks = 0; ks < 2; ks++) {
      short8 af[4], bfv[4];
#pragma unroll
      for (int m=0;m<4;m++){
        int r = wr*64 + m*16 + (lane & 15);
        int g = ks*4 + (lane >> 4);
        af[m] = *(const short8*)(As + r*64 + ((g ^ (r&7))<<3));
      }
#pragma unroll
      for (int n=0;n<4;n++){
        int r = wc*64 + n*16 + (lane & 15);
        int g = ks*4 + (lane >> 4);
        bfv[n] = *(const short8*)(Bs + r*64 + ((g ^ (r&7))<<3));
      }
#pragma unroll
      for (int m=0;m<4;m++)
#pragma unroll
        for (int n=0;n<4;n++)
          acc[m][n] = __builtin_amdgcn_mfma_f32_16x16x32_bf16(af[m], bfv[n], acc[m][n], 0, 0, 0);
    }
  };

  stage(0, 0);
  __syncthreads();
#pragma unroll
  for (int t = 0; t < 4; t++){
    if (t < 3) stage((t+1)&1, (t+1)*64);
    compute(t&1);
    __syncthreads();
  }

  // epilogue. C/D frag layout: col=lane&15, row=(lane>>4)*4+reg
  if (OUTMODE == 0) {
    float bcol[4];
#pragma unroll
    for (int n=0;n<4;n++){
      int col = col0 + wc*64 + n*16 + (lane&15);
      bcol[n] = (col < 256) ? bias[col] : 0.f;
    }
#pragma unroll
    for (int m=0;m<4;m++){
#pragma unroll
      for (int n=0;n<4;n++){
        int col = wc*64 + n*16 + (lane&15);
        int cg = col >> 3;
#pragma unroll
        for (int rg=0;rg<4;rg++){
          int row = wr*64 + m*16 + ((lane>>4)<<2) + rg;
          smem[row*128 + ((cg ^ (row&7))<<3) + (col&7)] = (short)f2bf(acc[m][n][rg] + bcol[n]);
        }
      }
    }
    __syncthreads();
    int row = tid >> 1, ch = tid & 1;
    long grow = row0 + row;
#pragma unroll
    for (int j=0;j<8;j++){
      int cg = ch*8 + j;
      short8 v = *(const short8*)(smem + row*128 + ((cg ^ (row&7))<<3));
      int col = col0 + cg*8;
      if (col0 < 256) *(short8*)(out_q + grow*256 + col)        = v;
      else            *(short8*)(out_kv + grow*512 + (col-256)) = v;
    }
  } else {
    float* fs = (float*)smem;
#pragma unroll
    for (int m=0;m<4;m++){
#pragma unroll
      for (int n=0;n<4;n++){
        int col = wc*64 + n*16 + (lane&15);
        int c4 = col >> 2;
        float bv = bias[col0 + col];
#pragma unroll
        for (int rg=0;rg<4;rg++){
          int row = wr*64 + m*16 + ((lane>>4)<<2) + rg;
          fs[row*128 + ((c4 ^ (row&7))<<2) + (col&3)] = acc[m][n][rg] + bv;
        }
      }
    }
    __syncthreads();
    int row = tid >> 1;
    long grow = row0 + row;
#pragma unroll
    for (int j=0;j<16;j++){
      int c4 = (tid&1)*16 + j;
      float4 v = *(const float4*)(fs + row*128 + ((c4 ^ (row&7))<<2));
      *(float4*)(out_f + grow*ND + col0 + c4*4) = v;
    }
  }
}

// ---------------- depthwise 3x3 stride-2 conv + BN + v_bias ------------------
// in: kv_buf bf16 (8,128,128,512) -> out: kv_ds bf16 (8,64,64,512)
// Lane = 16B channel chunk (lane owns ch 8*lane..8*lane+7): every wave-wide
// load is one contiguous 1KB input pixel. Weights/BN hoisted to registers;
// column reuse while walking 8 output pixels in x per wave.
__global__ __launch_bounds__(256) void dwconv_kernel(const short* __restrict__ kv_buf,
    const float* __restrict__ dw_w, const float* __restrict__ gamma,
    const float* __restrict__ beta, const float* __restrict__ mean,
    const float* __restrict__ var, const float* __restrict__ v_bias,
    short* __restrict__ kv_ds)
{
  const int bid = blockIdx.x;          // 8*64*2 = 1024 blocks
  const int b  = bid >> 7;
  const int rem = bid & 127;
  const int y2 = rem >> 1, xq = rem & 1;
  const int tid = threadIdx.x;
  const int lane = tid & 63, w = tid >> 6;
  const int ch0 = lane * 8;            // 8 channels per lane

  // fused BN scale/shift (+v_bias) for my 8 channels
  float s[8], sh[8];
#pragma unroll
  for (int i=0;i<8;i+=4){
    float4 g4 = *(const float4*)(gamma + ch0 + i);
    float4 v4 = *(const float4*)(var   + ch0 + i);
    float4 m4 = *(const float4*)(mean  + ch0 + i);
    float4 b4 = *(const float4*)(beta  + ch0 + i);
    float gg[4] = {g4.x,g4.y,g4.z,g4.w}, vv[4] = {v4.x,v4.y,v4.z,v4.w};
    float mm[4] = {m4.x,m4.y,m4.z,m4.w}, bb[4] = {b4.x,b4.y,b4.z,b4.w};
#pragma unroll
    for (int j=0;j<4;j++){
      float sv = gg[j] * rsqrtf(vv[j] + 1e-3f);
      s[i+j]  = sv;
      sh[i+j] = bb[j] - mm[j]*sv;
    }
  }
  if (ch0 >= 256){
    float4 vb0 = *(const float4*)(v_bias + ch0 - 256);
    float4 vb1 = *(const float4*)(v_bias + ch0 - 252);
    sh[0]+=vb0.x; sh[1]+=vb0.y; sh[2]+=vb0.z; sh[3]+=vb0.w;
    sh[4]+=vb1.x; sh[5]+=vb1.y; sh[6]+=vb1.z; sh[7]+=vb1.w;
  }

  // weights: 9 taps x 8 channels, in registers
  float wv[9][8];
#pragma unroll
  for (int t=0;t<9;t++){
    float4 w0 = *(const float4*)(dw_w + t*512 + ch0);
    float4 w1 = *(const float4*)(dw_w + t*512 + ch0 + 4);
    wv[t][0]=w0.x; wv[t][1]=w0.y; wv[t][2]=w0.z; wv[t][3]=w0.w;
    wv[t][4]=w1.x; wv[t][5]=w1.y; wv[t][6]=w1.z; wv[t][7]=w1.w;
  }

  const int y0 = y2*2;
  const bool vy2 = (y0 + 2) < 128;
  const short* r0 = kv_buf + (((long)b*128 + y0)*128)*512 + ch0;
  const short* r1 = r0 + 128*512;
  const short* r2 = r1 + 128*512;
  const short8 zero8 = {0,0,0,0,0,0,0,0};

  const int x2base = xq*32 + w*8;      // this wave's first output x
  const int xs = x2base*2;             // first input column

  auto ld = [&](const short* r, int x, bool vy)->short8 {
    if (vy && x < 128) return *(const short8*)(r + (long)x*512);
    return zero8;
  };

  // left column (input x = xs) for the 3 rows
  short8 L0 = ld(r0, xs, true), L1 = ld(r1, xs, true), L2 = ld(r2, xs, vy2);

#pragma unroll
  for (int i=0;i<8;i++){
    const int x2 = x2base + i;
    const int xm = xs + 2*i + 1, xr = xs + 2*i + 2;
    short8 M0 = ld(r0, xm, true), M1 = ld(r1, xm, true), M2 = ld(r2, xm, vy2);
    short8 R0 = ld(r0, xr, true), R1 = ld(r1, xr, true), R2 = ld(r2, xr, vy2);

    float acc[8];
#pragma unroll
    for (int c=0;c<8;c++) acc[c] = 0.f;
#pragma unroll
    for (int c=0;c<8;c++){
      acc[c] += bf2f((unsigned short)L0[c]) * wv[0][c];
      acc[c] += bf2f((unsigned short)M0[c]) * wv[1][c];
      acc[c] += bf2f((unsigned short)R0[c]) * wv[2][c];
      acc[c] += bf2f((unsigned short)L1[c]) * wv[3][c];
      acc[c] += bf2f((unsigned short)M1[c]) * wv[4][c];
      acc[c] += bf2f((unsigned short)R1[c]) * wv[5][c];
      acc[c] += bf2f((unsigned short)L2[c]) * wv[6][c];
      acc[c] += bf2f((unsigned short)M2[c]) * wv[7][c];
      acc[c] += bf2f((unsigned short)R2[c]) * wv[8][c];
    }
    short8 o;
#pragma unroll
    for (int c=0;c<8;c++) o[c] = (short)f2bf(acc[c]*s[c] + sh[c]);
    *(short8*)(kv_ds + ((long)((b*64+y2)*64 + x2))*512 + ch0) = o;

    L0 = R0; L1 = R1; L2 = R2;
  }
}

// ---------------- halo attention --------------------------------------------
// grid: 2048 (= 8 batch * 256 windows); block: 256 (4 waves, each 2 heads)
__global__ __launch_bounds__(256) void halo_attn_kernel(const short* __restrict__ q_buf,
    const short* __restrict__ kv_ds, const float* __restrict__ relb,
    const float* __restrict__ scale, short* __restrict__ attn_out)
{
  __shared__ float qss[8][64];
  __shared__ float kss[8][64];
  __shared__ short vts[4][32][72];  // per-wave V^T [dim][key], 144B rows (16B aligned)
  __shared__ short ps [4][64][72];  // per-wave P   [query][key]

  const int bid = blockIdx.x;
  const int b = bid >> 8, wno = bid & 255;
  const int bi = wno >> 4, bj = wno & 15;
  const int tid = threadIdx.x;
  const int w = tid >> 6, lane = tid & 63;

  // ---- sum-of-squares prepass (for post-hoc l2 normalization) ----
#pragma unroll
  for (int i=0;i<4;i++){
    int idx = i*256 + tid;        // 0..1023: [0,512) q rows, [512,1024) k rows
    int isk = idx >> 9;
    int h   = (idx >> 6) & 7;
    int row = idx & 63;
    float ss = 0.f;
    if (!isk) {
      int qy = row>>3, qx = row&7;
      const short* p = q_buf + ((long)((b*128 + bi*8 + qy)*128 + (bj*8+qx)))*256 + h*32;
#pragma unroll
      for (int j=0;j<4;j++){
        short8 v = *(const short8*)(p + j*8);
#pragma unroll
        for (int e=0;e<8;e++){ float f = bf2f((unsigned short)v[e]); ss += f*f; }
      }
      qss[h][row] = fmaxf(ss, 1.55e-5f);
    } else {
      int ky = row>>3, kx = row&7;
      int yy = bi*4 - 2 + ky, xx = bj*4 - 2 + kx;
      if (yy>=0 && yy<64 && xx>=0 && xx<64) {
        const short* p = kv_ds + ((long)((b*64+yy)*64+xx))*512 + h*32;
#pragma unroll
        for (int j=0;j<4;j++){
          short8 v = *(const short8*)(p + j*8);
#pragma unroll
          for (int e=0;e<8;e++){ float f = bf2f((unsigned short)v[e]); ss += f*f; }
        }
      }
      kss[h][row] = fmaxf(ss, 1.55e-5f);
    }
  }
  __syncthreads();

  const short8 zero8 = {0,0,0,0,0,0,0,0};

  for (int hi=0; hi<2; hi++){
    int h = w + hi*4;
    float lscale = __expf(fminf(scale[h], 4.6051702f)); // exp(min(s, ln 100))

    // ---- stage V^T (per wave) ----
#pragma unroll 4
    for (int j=0;j<32;j++){
      int flat = j*64 + lane;
      int key = flat >> 5, d = flat & 31;
      int ky = key>>3, kx = key&7;
      int yy = bi*4-2+ky, xx = bj*4-2+kx;
      short val = 0;
      if (yy>=0 && yy<64 && xx>=0 && xx<64)
        val = kv_ds[((long)((b*64+yy)*64+xx))*512 + 256 + h*32 + d];
      vts[w][d][key] = val;
    }

    // ---- S^T = K * Q^T  (raw, unnormalized) ----
    short8 af[4], bfv[4];
#pragma unroll
    for (int m=0;m<4;m++){
      int key = m*16 + (lane&15);
      int ky = key>>3, kx = key&7;
      int yy = bi*4-2+ky, xx = bj*4-2+kx;
      if (yy>=0 && yy<64 && xx>=0 && xx<64)
        af[m] = *(const short8*)(kv_ds + ((long)((b*64+yy)*64+xx))*512 + h*32 + ((lane>>4)<<3));
      else
        af[m] = zero8;
    }
#pragma unroll
    for (int n=0;n<4;n++){
      int q = n*16 + (lane&15);
      int qy = q>>3, qx = q&7;
      bfv[n] = *(const short8*)(q_buf + ((long)((b*128+bi*8+qy)*128 + bj*8+qx))*256 + h*32 + ((lane>>4)<<3));
    }
    f32x4 sc_[4][4];
#pragma unroll
    for (int m=0;m<4;m++)
#pragma unroll
      for (int n=0;n<4;n++)
        sc_[m][n] = __builtin_amdgcn_mfma_f32_16x16x32_bf16(af[m], bfv[n],
                        (f32x4){0.f,0.f,0.f,0.f}, 0, 0, 0);

    // ---- logits: scale + rel bias + pad mask; key=m*16+(lane>>4)*4+reg, query=n*16+(lane&15)
    float rq[4];
#pragma unroll
    for (int n=0;n<4;n++) rq[n] = rsqrtf(qss[h][n*16 + (lane&15)]);
    float mx[4] = {-1e30f,-1e30f,-1e30f,-1e30f};
#pragma unroll
    for (int m=0;m<4;m++){
      int key0 = m*16 + ((lane>>4)<<2);
      float rk[4], mk[4];
#pragma unroll
      for (int r=0;r<4;r++){
        int key = key0 + r;
        int ky = key>>3, kx = key&7;
        int yy = bi*4-2+ky, xx = bj*4-2+kx;
        rk[r] = rsqrtf(kss[h][key]);
        mk[r] = (yy>=0 && yy<64 && xx>=0 && xx<64) ? 0.f : -100.f;
      }
#pragma unroll
      for (int n=0;n<4;n++){
        int q = n*16 + (lane&15);
        f32x4 rb = *(const f32x4*)(relb + h*4096 + q*64 + key0);
#pragma unroll
        for (int r=0;r<4;r++){
          float v = sc_[m][n][r] * (rk[r]*rq[n]*lscale) + rb[r] + mk[r];
          sc_[m][n][r] = v;
          mx[n] = fmaxf(mx[n], v);
        }
      }
    }
#pragma unroll
    for (int n=0;n<4;n++){
      mx[n] = fmaxf(mx[n], __shfl_xor(mx[n], 16));
      mx[n] = fmaxf(mx[n], __shfl_xor(mx[n], 32));
    }
    float sm[4] = {0.f,0.f,0.f,0.f};
#pragma unroll
    for (int m=0;m<4;m++)
#pragma unroll
      for (int n=0;n<4;n++)
#pragma unroll
        for (int r=0;r<4;r++){
          float e = __expf(sc_[m][n][r] - mx[n]);
          sc_[m][n][r] = e;
          sm[n] += e;
        }
#pragma unroll
    for (int n=0;n<4;n++){
      sm[n] += __shfl_xor(sm[n], 16);
      sm[n] += __shfl_xor(sm[n], 32);
      sm[n] = 1.f / sm[n];
    }
    // ---- write P[query][key] (consecutive regs are consecutive keys -> b64) ----
#pragma unroll
    for (int n=0;n<4;n++){
      int q = n*16 + (lane&15);
#pragma unroll
      for (int m=0;m<4;m++){
        short4v pk;
#pragma unroll
        for (int r=0;r<4;r++) pk[r] = (short)f2bf(sc_[m][n][r] * sm[n]);
        *(short4v*)(&ps[w][q][m*16 + ((lane>>4)<<2)]) = pk;
      }
    }
    __syncthreads();

    // ---- O = P * V ----
    f32x4 oc[4][2];
#pragma unroll
    for (int m=0;m<4;m++)
#pragma unroll
      for (int n=0;n<2;n++) oc[m][n] = (f32x4){0.f,0.f,0.f,0.f};
#pragma unroll
    for (int ks=0; ks<2; ks++){
      short8 pa[4], vb[2];
#pragma unroll
      for (int m=0;m<4;m++)
        pa[m] = *(const short8*)(&ps[w][m*16 + (lane&15)][ks*32 + ((lane>>4)<<3)]);
#pragma unroll
      for (int n=0;n<2;n++)
        vb[n] = *(const short8*)(&vts[w][n*16 + (lane&15)][ks*32 + ((lane>>4)<<3)]);
#pragma unroll
      for (int m=0;m<4;m++)
#pragma unroll
        for (int n=0;n<2;n++)
          oc[m][n] = __builtin_amdgcn_mfma_f32_16x16x32_bf16(pa[m], vb[n], oc[m][n], 0, 0, 0);
    }
    // ---- store: query=m*16+(lane>>4)*4+reg, dim=n*16+(lane&15) ----
#pragma unroll
    for (int m=0;m<4;m++){
      int q0 = m*16 + ((lane>>4)<<2);
#pragma unroll
      for (int n=0;n<2;n++){
        int d = n*16 + (lane&15);
#pragma unroll
        for (int r=0;r<4;r++){
          int q = q0 + r;
          int qy = q>>3, qx = q&7;
          attn_out[((long)((b*128 + bi*8+qy)*128 + bj*8+qx))*256 + h*32 + d] =
              (short)f2bf(oc[m][n][r]);
        }
      }
    }
    __syncthreads();
  }
}

// ---------------- launch -----------------------------------------------------
extern "C" void kernel_launch(void* const* d_in, const int* in_sizes, int n_in,
                              void* d_out, int out_size, void* d_ws, size_t ws_size,
                              hipStream_t stream)
{
  (void)in_sizes; (void)n_in; (void)out_size; (void)ws_size;
  const float* inputs = (const float*)d_in[0];
  const float* qkv_w  = (const float*)d_in[1];
  const float* q_bias = (const float*)d_in[2];
  const float* v_bias = (const float*)d_in[3];
  const float* dw_w   = (const float*)d_in[4];
  const float* dw_g   = (const float*)d_in[5];
  const float* dw_b   = (const float*)d_in[6];
  const float* dw_m   = (const float*)d_in[7];
  const float* dw_v   = (const float*)d_in[8];
  const float* scale  = (const float*)d_in[9];
  const float* cpb_w1 = (const float*)d_in[10];
  const float* cpb_b1 = (const float*)d_in[11];
  const float* cpb_w2 = (const float*)d_in[12];
  const float* proj_w = (const float*)d_in[13];
  const float* proj_b = (const float*)d_in[14];

  char* ws = (char*)d_ws;
  short* q_buf    = (short*)(ws);                  //  64 MiB  (131072 x 256 bf16)
  short* kv_buf   = (short*)(ws + 67108864L);      // 128 MiB  (131072 x 512 bf16)
  short* kv_ds    = (short*)(ws + 201326592L);     //  32 MiB  (8x64x64x512 bf16)
  short* attn_buf = (short*)(ws + 234881024L);     //  64 MiB  (131072 x 256 bf16)
  short* qkvw_t   = (short*)(ws + 301989888L);     // 384 KiB  (768 x 256 bf16)
  short* projw_t  = (short*)(ws + 302383104L);     // 128 KiB  (256 x 256 bf16)
  float* relb     = (float*)(ws + 302514176L);     // 128 KiB  (8 x 64 x 64 f32)

  // a_bf reuses the attn_buf region (dead until the attention kernel runs,
  // and a_bf is dead before attention writes it).
  short* a_bf = attn_buf;

  cvt_bf16_kernel<<<2048, 256, 0, stream>>>(inputs, a_bf, 4194304L);
  transpose_w_kernel<<<768, 256, 0, stream>>>(qkv_w, qkvw_t, 256, 768);
  transpose_w_kernel<<<256, 256, 0, stream>>>(proj_w, projw_t, 256, 256);
  relbias_kernel<<<64, 64, 0, stream>>>(cpb_w1, cpb_b1, cpb_w2, relb);

  gemm_bt_kernel<768, 0><<<6144, 256, 0, stream>>>(
      a_bf, qkvw_t, q_bias, q_buf, kv_buf, nullptr);

  dwconv_kernel<<<1024, 256, 0, stream>>>(kv_buf, dw_w, dw_g, dw_b, dw_m, dw_v, v_bias, kv_ds);

  halo_attn_kernel<<<2048, 256, 0, stream>>>(q_buf, kv_ds, relb, scale, attn_buf);

  gemm_bt_kernel<256, 1><<<2048, 256, 0, stream>>>(
      attn_buf, projw_t, proj_b, nullptr, nullptr, (float*)d_out);
}